// Round 8
// baseline (319.717 us; speedup 1.0000x reference)
//
#include <hip/hip_runtime.h>

// BiMPNN layer, MI355X. f32 I/O, bf16 MFMA internally.
//   agg  = A  @ (h@W^T  + b)  ==  (A @ h) @ W^T  + deg_out * b   (linearity)
//   aggt = A^T@ (h@Wt^T + bt) ==  (A^T@ h) @ Wt^T + deg_in  * bt
// R8: (a) k_aggsort LDS diet: no words[] buffer (histogram + scatter both read
// the slab from global; 2nd read is L2-warm) -> 12.8 KB LDS -> 8 blocks/CU
// (was 22.5 KB / 54% occupancy). (b) k_bin caches its 25 edges/thread in VGPRs
// across histogram->scatter (one global pass over rows/cols instead of two).

typedef __bf16 bf16;
typedef __bf16 bf16x4 __attribute__((ext_vector_type(4)));
typedef __bf16 bf16x8 __attribute__((ext_vector_type(8)));
typedef float  f32x4  __attribute__((ext_vector_type(4)));
typedef unsigned int u32;
typedef u32 u32x4 __attribute__((ext_vector_type(4)));
typedef unsigned short u16;

#define D 128
#define CAPC 2432      // max real edges/bucket (mean 2046, +8.5 sigma)
#define SLAB 2816      // CAPC + 128*3 pad slots (pad-to-4 worst case)
#define BIN_CHUNK 6400 // 25 * 256 edges per k_bin block
#define EPT 25         // edges per thread in k_bin

// Binning (y=0,1) + cast plane (y=2). packed word: (node&127)<<17 | src.
__global__ __launch_bounds__(256) void k_bin(
    const int* __restrict__ rows, const int* __restrict__ cols,
    int* __restrict__ gcnt_f, int* __restrict__ gcnt_r,
    u32* __restrict__ buf_f, u32* __restrict__ buf_r, int E, int B,
    const float* __restrict__ h,
    const float* __restrict__ Ws_w, const float* __restrict__ W_w,
    const float* __restrict__ Wt_w,
    bf16* __restrict__ h_bf, bf16* __restrict__ wbf, int n4h) {
    __shared__ int hist[1024];    // counts -> cursors
    __shared__ int lbase[1024];   // local exclusive base
    __shared__ int gbase[1024];   // global reserved base
    __shared__ int tsum[256];
    __shared__ u32 sorted[BIN_CHUNK];
    __shared__ u16 btag[BIN_CHUNK];
    int t = threadIdx.x;

    if (blockIdx.y == 2) {        // ---- cast plane: h->bf16, pad row, weights
        int stride = gridDim.x * 256;
        int ncast = n4h + 32 + 12288;
        for (int i = blockIdx.x * 256 + t; i < ncast; i += stride) {
            if (i < n4h) {
                f32x4 v = *(const f32x4*)&h[i * 4];
                bf16x4 o;
                o.x = (bf16)v.x; o.y = (bf16)v.y; o.z = (bf16)v.z; o.w = (bf16)v.w;
                *(bf16x4*)&h_bf[i * 4] = o;
            } else if (i < n4h + 32) {
                int k = i - n4h;
                bf16x4 z; z.x = (bf16)0.f; z.y = (bf16)0.f; z.z = (bf16)0.f; z.w = (bf16)0.f;
                *(bf16x4*)&h_bf[(size_t)n4h * 4 + k * 4] = z;
            } else {
                int k = i - n4h - 32;
                const float* src = (k < 4096) ? Ws_w : (k < 8192) ? W_w : Wt_w;
                int kk = k & 4095;
                f32x4 v = *(const f32x4*)&src[kk * 4];
                bf16x4 o;
                o.x = (bf16)v.x; o.y = (bf16)v.y; o.z = (bf16)v.z; o.w = (bf16)v.w;
                *(bf16x4*)&wbf[k * 4] = o;
            }
        }
        return;
    }

    int dir = blockIdx.y;
    const int* key = dir ? cols : rows;
    const int* pay = dir ? rows : cols;
    int* gcnt = dir ? gcnt_r : gcnt_f;
    u32* buf  = dir ? buf_r : buf_f;
    int base = blockIdx.x * BIN_CHUNK;

    for (int b = t; b < 1024; b += 256) hist[b] = 0;
    __syncthreads();
    int kv[EPT], pv[EPT];         // edges cached in VGPRs across both passes
#pragma unroll
    for (int i = 0; i < EPT; ++i) {
        int e = base + i * 256 + t;
        if (e < E) {
            kv[i] = key[e]; pv[i] = pay[e];
            atomicAdd(&hist[kv[i] >> 7], 1);
        }
    }
    __syncthreads();
    // two-level exclusive scan over 1024 buckets (4 consecutive per thread)
    int s0 = hist[t * 4], s1 = hist[t * 4 + 1], s2 = hist[t * 4 + 2], s3 = hist[t * 4 + 3];
    tsum[t] = s0 + s1 + s2 + s3;
    __syncthreads();
    for (int o = 1; o < 256; o <<= 1) {
        int v = (t >= o) ? tsum[t - o] : 0;
        __syncthreads();
        tsum[t] += v;
        __syncthreads();
    }
    int run = (t > 0) ? tsum[t - 1] : 0;
    lbase[t * 4]     = run;
    lbase[t * 4 + 1] = run + s0;
    lbase[t * 4 + 2] = run + s0 + s1;
    lbase[t * 4 + 3] = run + s0 + s1 + s2;
    __syncthreads();
    int total = tsum[255];
    for (int b = t; b < 1024; b += 256) {
        int nxt = (b < 1023) ? lbase[b + 1] : total;
        int c = nxt - lbase[b];
        gbase[b] = (c && b < B) ? atomicAdd(&gcnt[b], c) : 0;
        hist[b] = lbase[b];
    }
    __syncthreads();
#pragma unroll
    for (int i = 0; i < EPT; ++i) {
        int e = base + i * 256 + t;
        if (e < E) {
            int k = kv[i], p = pv[i];
            int b = k >> 7;
            int pos = atomicAdd(&hist[b], 1);
            sorted[pos] = ((u32)(k & 127) << 17) | (u32)p;
            btag[pos] = (u16)b;
        }
    }
    __syncthreads();
    // edge-parallel copy-out (coalesced within bucket runs)
    for (int i = t; i < total; i += 256) {
        int b = btag[i];
        int gp = gbase[b] + (i - lbase[b]);
        if (gp < CAPC) buf[(size_t)b * SLAB + gp] = sorted[i];
    }
}

__device__ __forceinline__ float blo(u32 w) { return __uint_as_float(w << 16); }
__device__ __forceinline__ float bhi(u32 w) { return __uint_as_float(w & 0xffff0000u); }

// Fused per-bucket sort + aggregation, slim LDS (12.8 KB -> 8 blocks/CU).
// 1) histogram by local node (global read of slab); 2) padded-scan; 3) scatter
// (global re-read, L2-warm) into LDS sorted[] with pre-scaled row offsets,
// runs padded to x4 with PADV; 4) each wave aggregates 32 nodes quarter-wave
// (16 lanes x 16B dwordx4, 4 edges per wave-inst). Emits AH/ATH (bf16) + deg.
__global__ __launch_bounds__(256) void k_aggsort(
    const u32* __restrict__ h32,
    const int* __restrict__ gcnt_f, const int* __restrict__ gcnt_r,
    const u32* __restrict__ buf_f, const u32* __restrict__ buf_r,
    bf16* __restrict__ AH, bf16* __restrict__ ATH,
    int* __restrict__ deg_f, int* __restrict__ deg_r, int N, u32 PADV) {
    __shared__ u32 sorted[SLAB];
    __shared__ int hist[128], pscn[128], cursor[128];
    int t = threadIdx.x, bkt = blockIdx.x;
    const int* cp; const u32* buf; bf16* dst; int* deg;
    if (blockIdx.y == 0) { cp = gcnt_f; buf = buf_f + (size_t)bkt * SLAB; dst = AH;  deg = deg_f; }
    else                 { cp = gcnt_r; buf = buf_r + (size_t)bkt * SLAB; dst = ATH; deg = deg_r; }
    int cnt = cp[bkt]; if (cnt > CAPC) cnt = CAPC;
    if (t < 128) hist[t] = 0;
    __syncthreads();
    for (int i = t; i < cnt; i += 256)
        atomicAdd(&hist[buf[i] >> 17], 1);
    __syncthreads();
    int pd = 0;
    if (t < 128) { pd = (hist[t] + 3) & ~3; pscn[t] = pd; }
    __syncthreads();
    for (int o = 1; o < 128; o <<= 1) {          // inclusive scan of padded degs
        int v = (t < 128 && t >= o) ? pscn[t - o] : 0;
        __syncthreads();
        if (t < 128) pscn[t] += v;
        __syncthreads();
    }
    int ptot = pscn[127];
    if (t < 128) cursor[t] = pscn[t] - pd;
    __syncthreads();
    for (int i = t; i < ptot; i += 256) sorted[i] = PADV;
    __syncthreads();
    for (int i = t; i < cnt; i += 256) {
        u32 w = buf[i];                           // L2-warm re-read
        int p = atomicAdd(&cursor[w >> 17], 1);
        sorted[p] = (w & 0x1FFFF) << 6;           // pre-scaled dword row offset
    }
    __syncthreads();

    // ---- aggregation phase: wave per node (32 nodes per wave, sequential)
    int wave = t >> 6, lane = t & 63;
    int q = lane >> 4, c = lane & 15;
    int node0 = bkt * 128;
    for (int ln = wave; ln < 128; ln += 4) {
        int node = node0 + ln;
        if (node >= N) continue;                  // wave-uniform
        int dg = hist[ln];
        int plen = (dg + 3) & ~3;
        int p = pscn[ln] - plen, pend = pscn[ln];
        float a0 = 0.f, a1 = 0.f, a2 = 0.f, a3 = 0.f;
        float a4 = 0.f, a5 = 0.f, a6 = 0.f, a7 = 0.f;
        for (; p + 15 < pend; p += 16) {
            u32 j0 = sorted[p + q],     j1 = sorted[p + 4 + q];
            u32 j2 = sorted[p + 8 + q], j3 = sorted[p + 12 + q];
            u32x4 w0 = *(const u32x4*)&h32[(size_t)j0 + c * 4];
            u32x4 w1 = *(const u32x4*)&h32[(size_t)j1 + c * 4];
            u32x4 w2 = *(const u32x4*)&h32[(size_t)j2 + c * 4];
            u32x4 w3 = *(const u32x4*)&h32[(size_t)j3 + c * 4];
            a0 += blo(w0.x); a1 += bhi(w0.x); a2 += blo(w0.y); a3 += bhi(w0.y);
            a4 += blo(w0.z); a5 += bhi(w0.z); a6 += blo(w0.w); a7 += bhi(w0.w);
            a0 += blo(w1.x); a1 += bhi(w1.x); a2 += blo(w1.y); a3 += bhi(w1.y);
            a4 += blo(w1.z); a5 += bhi(w1.z); a6 += blo(w1.w); a7 += bhi(w1.w);
            a0 += blo(w2.x); a1 += bhi(w2.x); a2 += blo(w2.y); a3 += bhi(w2.y);
            a4 += blo(w2.z); a5 += bhi(w2.z); a6 += blo(w2.w); a7 += bhi(w2.w);
            a0 += blo(w3.x); a1 += bhi(w3.x); a2 += blo(w3.y); a3 += bhi(w3.y);
            a4 += blo(w3.z); a5 += bhi(w3.z); a6 += blo(w3.w); a7 += bhi(w3.w);
        }
        for (; p + 3 < pend; p += 4) {
            u32 j = sorted[p + q];
            u32x4 w = *(const u32x4*)&h32[(size_t)j + c * 4];
            a0 += blo(w.x); a1 += bhi(w.x); a2 += blo(w.y); a3 += bhi(w.y);
            a4 += blo(w.z); a5 += bhi(w.z); a6 += blo(w.w); a7 += bhi(w.w);
        }
        a0 += __shfl_down(a0, 16); a1 += __shfl_down(a1, 16);
        a2 += __shfl_down(a2, 16); a3 += __shfl_down(a3, 16);
        a4 += __shfl_down(a4, 16); a5 += __shfl_down(a5, 16);
        a6 += __shfl_down(a6, 16); a7 += __shfl_down(a7, 16);
        a0 += __shfl_down(a0, 32); a1 += __shfl_down(a1, 32);
        a2 += __shfl_down(a2, 32); a3 += __shfl_down(a3, 32);
        a4 += __shfl_down(a4, 32); a5 += __shfl_down(a5, 32);
        a6 += __shfl_down(a6, 32); a7 += __shfl_down(a7, 32);
        if (lane < 16) {
            bf16x8 o;
            o[0] = (bf16)a0; o[1] = (bf16)a1; o[2] = (bf16)a2; o[3] = (bf16)a3;
            o[4] = (bf16)a4; o[5] = (bf16)a5; o[6] = (bf16)a6; o[7] = (bf16)a7;
            *(bf16x8*)&dst[(size_t)node * D + c * 8] = o;
        }
    }
    if (t < 128) {
        int node = node0 + t;
        if (node < N) deg[node] = hist[t];
    }
}

// Fused GEMM + bias + exact GELU. All-bf16 staging (weights pre-cast).
// A frag lane: m=lane&15, k=(lane>>4)*8+j; B frag same with n; C/D: col=lane&15,
// row=(lane>>4)*4+r. (k-permutation consistent between A and B staging.)
__global__ __launch_bounds__(256) void k_gemm(
    const bf16* __restrict__ h, const bf16* __restrict__ AH, const bf16* __restrict__ ATH,
    const bf16* __restrict__ wbf,   // [Ws|W|Wt], each 128x128
    const float* __restrict__ Ws_b, const float* __restrict__ W_b, const float* __restrict__ Wt_b,
    const int* __restrict__ deg_out, const int* __restrict__ deg_in,
    float* __restrict__ out, int N) {
    __shared__ __align__(16) bf16 Ash[128 * 32];
    __shared__ __align__(16) bf16 Bsh[128 * 32];
    int t = threadIdx.x;
    int lane = t & 63;
    int w = t >> 6;
    int wm = (w >> 1) * 64, wn = (w & 1) * 64;
    int m0 = blockIdx.x * 128;

    f32x4 acc[4][4];
#pragma unroll
    for (int i = 0; i < 4; ++i)
#pragma unroll
        for (int j = 0; j < 4; ++j)
            acc[i][j] = (f32x4){0.f, 0.f, 0.f, 0.f};

    for (int kc = 0; kc < 12; ++kc) {
        const bf16* X  = (kc < 4) ? h : (kc < 8) ? AH : ATH;
        const bf16* Wm = wbf + (kc >> 2) * (128 * 128);
        int c0 = (kc & 3) * 32;
#pragma unroll
        for (int r = 0; r < 2; ++r) {
            int v = r * 256 + t;
            int row = v >> 2, seg = v & 3;
            int xr = m0 + row; if (xr >= N) xr = N - 1;  // clamp, stores guarded
            *(bf16x8*)&Ash[row * 32 + seg * 8] =
                *(const bf16x8*)&X[(size_t)xr * D + c0 + seg * 8];
            *(bf16x8*)&Bsh[row * 32 + seg * 8] =
                *(const bf16x8*)&Wm[row * D + c0 + seg * 8];
        }
        __syncthreads();
        int kg = lane >> 4, lr = lane & 15;
        bf16x8 a[4], b[4];
#pragma unroll
        for (int i = 0; i < 4; ++i) {
            a[i] = *(const bf16x8*)&Ash[(wm + i * 16 + lr) * 32 + kg * 8];
            b[i] = *(const bf16x8*)&Bsh[(wn + i * 16 + lr) * 32 + kg * 8];
        }
#pragma unroll
        for (int i = 0; i < 4; ++i)
#pragma unroll
            for (int j = 0; j < 4; ++j)
                acc[i][j] = __builtin_amdgcn_mfma_f32_16x16x32_bf16(
                    a[i], b[j], acc[i][j], 0, 0, 0);
        __syncthreads();
    }

    int lr = lane & 15, lq = lane >> 4;
#pragma unroll
    for (int i = 0; i < 4; ++i) {
#pragma unroll
        for (int r = 0; r < 4; ++r) {
            int node = m0 + wm + i * 16 + lq * 4 + r;
            if (node >= N) continue;
            float fdr = (float)deg_out[node], fdc = (float)deg_in[node];
#pragma unroll
            for (int j = 0; j < 4; ++j) {
                int f = wn + j * 16 + lr;
                float val = acc[i][j][r] + Ws_b[f] + fdr * W_b[f] + fdc * Wt_b[f];
                float g = 0.5f * val * (1.0f + erff(val * 0.70710678118654752f));
                out[(size_t)node * D + f] = g;
            }
        }
    }
}

extern "C" void kernel_launch(void* const* d_in, const int* in_sizes, int n_in,
                              void* d_out, int out_size, void* d_ws, size_t ws_size,
                              hipStream_t stream) {
    const float* h    = (const float*)d_in[0];
    const float* W_w  = (const float*)d_in[1];
    const float* W_b  = (const float*)d_in[2];
    const float* Wt_w = (const float*)d_in[3];
    const float* Wt_b = (const float*)d_in[4];
    const float* Ws_w = (const float*)d_in[5];
    const float* Ws_b = (const float*)d_in[6];
    const int*   rows = (const int*)d_in[7];
    const int*   cols = (const int*)d_in[8];
    float* out = (float*)d_out;

    const int N = in_sizes[0] / D;        // 100000
    const int E = in_sizes[7];            // 1600000
    const int B = (N + 127) >> 7;         // 782 buckets

    char* ws = (char*)d_ws;
    size_t off = 0;
    auto take = [&](size_t bytes) -> char* {
        char* p = ws + off;
        off += (bytes + 511) & ~(size_t)511;
        return p;
    };
    bf16* h_bf    = (bf16*)take((size_t)(N + 1) * D * sizeof(bf16)); // +1 zero row
    bf16* AH      = (bf16*)take((size_t)N * D * sizeof(bf16));
    bf16* ATH     = (bf16*)take((size_t)N * D * sizeof(bf16));
    bf16* wbf     = (bf16*)take((size_t)3 * 128 * 128 * sizeof(bf16));
    int*  gcnt    = (int*)take((size_t)2 * B * sizeof(int));
    int*  deg_f   = (int*)take((size_t)N * sizeof(int));
    int*  deg_r   = (int*)take((size_t)N * sizeof(int));
    u32*  buf_f   = (u32*)take((size_t)B * SLAB * sizeof(u32));      // 8.8 MB
    u32*  buf_r   = (u32*)take((size_t)B * SLAB * sizeof(u32));      // 8.8 MB
    int*  gcnt_f = gcnt, *gcnt_r = gcnt + B;

    hipMemsetAsync(gcnt, 0, (size_t)2 * B * sizeof(int), stream);

    int n4h = N * D / 4;
    dim3 gbin((E + BIN_CHUNK - 1) / BIN_CHUNK, 3);   // y=0,1: bin dirs; y=2: cast
    k_bin<<<gbin, 256, 0, stream>>>(rows, cols, gcnt_f, gcnt_r, buf_f, buf_r,
                                    E, B, h, Ws_w, W_w, Wt_w, h_bf, wbf, n4h);
    dim3 gagg(B, 2);
    k_aggsort<<<gagg, 256, 0, stream>>>((const u32*)h_bf, gcnt_f, gcnt_r,
                                        buf_f, buf_r, AH, ATH,
                                        deg_f, deg_r, N, (u32)N << 6);
    k_gemm<<<B, 256, 0, stream>>>(h_bf, AH, ATH, wbf,
                                  Ws_b, W_b, Wt_b,
                                  deg_f, deg_r, out, N);
}